// Round 11
// baseline (491.647 us; speedup 1.0000x reference)
//
#include <hip/hip_runtime.h>

// MoE FFN (8 experts, top-2) — round 11: GEMM1 upgraded to 256x256 / BK=64 /
// 8-wave 2-phase schedule (T3-minimum, m248-class); GEMM2 + rest = round 10.

typedef unsigned short u16;
typedef __bf16 bf16x8 __attribute__((ext_vector_type(8)));
typedef float  f32x4  __attribute__((ext_vector_type(4)));

#define NTOK 4096
#define HID  1024
#define EDIM 4096
#define NEXP 8
#define MAXMT 72     // 128-row tiles: sum ceil(cnt_e/128) <= 64 + 8
#define MAXMT2 40    // 256-row tiles: sum ceil(cnt_e/256) <= 32 + 8

__device__ __forceinline__ u16 f32_bf16(float f) {
  unsigned int u = __float_as_uint(f);
  u += 0x7FFFu + ((u >> 16) & 1u);   // RNE
  return (u16)(u >> 16);
}

// ---------------- gating: one wave per token (+ fused x->bf16) ----------------
__global__ void gate_kernel(const float* __restrict__ x,
                            const float* __restrict__ Wg,
                            const float* __restrict__ bg,
                            float* __restrict__ combine,
                            float* __restrict__ counts,
                            int* __restrict__ icnt,
                            int* __restrict__ top2idx,
                            float* __restrict__ top2g,
                            u16* __restrict__ xbf) {
  __shared__ float lc[NEXP];
  int t = threadIdx.x;
  if (t < NEXP) lc[t] = 0.f;
  __syncthreads();
  int token = blockIdx.x * 4 + (t >> 6);
  int lane = t & 63;
  float s[NEXP] = {};
  const float* xr = x + (size_t)token * HID;
  u16* xb = xbf + (size_t)token * HID;
  for (int h = lane; h < HID; h += 64) {
    float xv = xr[h];
    xb[h] = f32_bf16(xv);                       // fused conversion
    const float* wrow = Wg + (size_t)h * NEXP;
#pragma unroll
    for (int e = 0; e < NEXP; ++e) s[e] += xv * wrow[e];
  }
#pragma unroll
  for (int off = 32; off > 0; off >>= 1) {
#pragma unroll
    for (int e = 0; e < NEXP; ++e) s[e] += __shfl_xor(s[e], off);
  }
  float m = -1e30f;
#pragma unroll
  for (int e = 0; e < NEXP; ++e) { s[e] += bg[e]; m = fmaxf(m, s[e]); }
  float p[NEXP]; float sum = 0.f;
#pragma unroll
  for (int e = 0; e < NEXP; ++e) { p[e] = expf(s[e] - m); sum += p[e]; }
  float inv = 1.f / sum;
#pragma unroll
  for (int e = 0; e < NEXP; ++e) p[e] *= inv;
  int i1 = 0; float g1 = p[0];
#pragma unroll
  for (int e = 1; e < NEXP; ++e) if (p[e] > g1) { g1 = p[e]; i1 = e; }
  int i2 = -1; float g2 = -1.f;
#pragma unroll
  for (int e = 0; e < NEXP; ++e) if (e != i1 && p[e] > g2) { g2 = p[e]; i2 = e; }
  float ginv = 1.f / (g1 + g2);
  if (lane == 0) {
#pragma unroll
    for (int e = 0; e < NEXP; ++e) {
      float c = (e == i1) ? g1 * ginv : (e == i2) ? g2 * ginv : 0.f;
      combine[(size_t)token * NEXP + e] = c;
      atomicAdd(&lc[e], p[e]);
    }
    top2idx[token * 2] = i1; top2idx[token * 2 + 1] = i2;
    top2g[token * 2] = g1 * ginv; top2g[token * 2 + 1] = g2 * ginv;
    atomicAdd(&icnt[i1], 1); atomicAdd(&icnt[i2], 1);
  }
  __syncthreads();
  if (t < NEXP) atomicAdd(&counts[t], lc[t]);
}

__global__ void aux_kernel(const float* __restrict__ counts, float* __restrict__ aux_out) {
  float s = 0.f;
#pragma unroll
  for (int e = 0; e < NEXP; ++e) s += counts[e];
  float a = 0.f;
#pragma unroll
  for (int e = 0; e < NEXP; ++e) a += (counts[e] / s) * (counts[e] / (float)NTOK);
  aux_out[0] = (float)NEXP * a;
}

// ---------------- routing: 128- and 256-row tiles + aux + scatter ------------
__global__ void route_kernel(const int* __restrict__ icnt,
                             const float* __restrict__ counts,
                             const int* __restrict__ top2idx,
                             int* __restrict__ nmtP,
                             int* __restrict__ mtE, int* __restrict__ mtRow0,
                             int* __restrict__ mtValid,
                             int* __restrict__ nmtP2,
                             int* __restrict__ mtE2, int* __restrict__ mtRow02,
                             int* __restrict__ mtValid2,
                             int* __restrict__ tok,
                             float* __restrict__ aux_out) {
  __shared__ int l_off[NEXP];
  __shared__ int l_cur[NEXP];
  int t = threadIdx.x;
  if (t == 0) {
    int s = 0, nm = 0, nm2 = 0;
    for (int e = 0; e < NEXP; ++e) {
      l_off[e] = s; l_cur[e] = 0;
      int c = icnt[e];
      int tiles = (c + 127) >> 7;
      for (int mt = 0; mt < tiles; ++mt) {
        mtE[nm] = e; mtRow0[nm] = s + (mt << 7);
        int v = c - (mt << 7); mtValid[nm] = v > 128 ? 128 : v;
        nm++;
      }
      int tiles2 = (c + 255) >> 8;
      for (int mt = 0; mt < tiles2; ++mt) {
        mtE2[nm2] = e; mtRow02[nm2] = s + (mt << 8);
        int v = c - (mt << 8); mtValid2[nm2] = v > 256 ? 256 : v;
        nm2++;
      }
      s += c;
    }
    nmtP[0] = nm;
    nmtP2[0] = nm2;
    float fs = 0.f;
    for (int e = 0; e < NEXP; ++e) fs += counts[e];
    float a = 0.f;
    for (int e = 0; e < NEXP; ++e) a += (counts[e] / fs) * (counts[e] / (float)NTOK);
    aux_out[0] = (float)NEXP * a;
  }
  __syncthreads();
  for (int i = t; i < NTOK * 2; i += 256) {
    int e = top2idx[i];
    int pos = atomicAdd(&l_cur[e], 1);
    tok[l_off[e] + pos] = (i >> 1) | ((i & 1) << 16);
  }
}

// ---------------- f32 [R][C] -> bf16 transposed [C][R], 64x64 tiles ----------
__global__ __launch_bounds__(256) void cvtT_kernel(const float* __restrict__ W,
                                                   u16* __restrict__ WT, int R, int C) {
  __shared__ u16 tile[64][66];
  int t = threadIdx.x;
  size_t eoff = (size_t)blockIdx.z * R * C;
  int c0 = blockIdx.x * 64, r0 = blockIdx.y * 64;
  const float* Wp = W + eoff + (size_t)r0 * C + c0;
  u16* WTp = WT + eoff + (size_t)c0 * R + r0;
#pragma unroll
  for (int p = 0; p < 4; ++p) {
    int idx = p * 256 + t;
    int row = idx >> 4;          // 0..63
    int col = (idx & 15) * 4;    // 0..60
    float4 v = *(const float4*)(Wp + (size_t)row * C + col);
    tile[row][col + 0] = f32_bf16(v.x);
    tile[row][col + 1] = f32_bf16(v.y);
    tile[row][col + 2] = f32_bf16(v.z);
    tile[row][col + 3] = f32_bf16(v.w);
  }
  __syncthreads();
#pragma unroll
  for (int p = 0; p < 4; ++p) {
    int idx = p * 256 + t;
    int oc = idx >> 4;           // output row (= source col), 0..63
    int orow = (idx & 15) * 4;   // position along R, 0..60
    ushort4 o;
    o.x = tile[orow + 0][oc];
    o.y = tile[orow + 1][oc];
    o.z = tile[orow + 2][oc];
    o.w = tile[orow + 3][oc];
    *(ushort4*)(WTp + (size_t)oc * R + orow) = o;
  }
}

// ---------------- GEMM1: 256x256 tile, BK=64, 8 waves, 2-phase schedule ------
// Catalog T3-minimum: per K-tile { stage(next) ; ds_read+MFMA(cur) ;
// lgkmcnt(0) ; vmcnt(0) ; barrier }. Chunk-XOR swizzle (chunk^=row&7, 8 chunks
// per 128B row — round-7-verified conflict-free). D^T epilogue.
// H[row][n] = bf16(relu(acc + b1[e][n])) for gathered token rows.
__global__ __launch_bounds__(512, 1) void gemm1_256(
    const u16* __restrict__ A, const u16* __restrict__ Wt,
    const int* __restrict__ nmtP2, const int* __restrict__ mtE2,
    const int* __restrict__ mtRow02, const int* __restrict__ mtValid2,
    const int* __restrict__ tok,
    const float* __restrict__ bias, u16* __restrict__ Hout)
{
  constexpr int KDIM = HID;        // 1024
  constexpr int NT   = EDIM / 256; // 16
  constexpr int NKT  = KDIM / 64;  // 16

  // bijective XCD swizzle (m204); mt-major (nt fastest) for B-panel L2 reuse
  const int nwg = gridDim.x;
  const int q = nwg >> 3, rr8 = nwg & 7;
  const int xcd = blockIdx.x & 7, jj = blockIdx.x >> 3;
  int item = (xcd < rr8 ? xcd * (q + 1) : rr8 * (q + 1) + (xcd - rr8) * q) + jj;

  if (item >= nmtP2[0] * NT) return;
  const int gmt = item / NT;
  const int nt  = item % NT;
  const int e = mtE2[gmt], row0 = mtRow02[gmt], valid = mtValid2[gmt];
  const int bn0 = nt << 8;

  __shared__ __align__(16) u16 As[2][256 * 64];   // 64 KB
  __shared__ __align__(16) u16 Bs[2][256 * 64];   // 64 KB

  const int t = threadIdx.x;
  const int lane = t & 63;
  const int w = t >> 6;                // 0..7
  const int wr = w >> 2, wc = w & 3;   // wave tile: rows wr*128, cols wc*64
  const int kq = lane >> 4;            // 0..3
  const int r  = lane & 15;
  const int srow = t >> 3;             // 0..63 (staging row within 64-row slab)
  const int schunk = t & 7;            // staging 16B chunk within 128B row

  const u16* Bb = Wt + ((size_t)e * EDIM + bn0) * KDIM;

  // per-thread gathered A row bases (4 slabs of 64 rows)
  size_t arow[4];
#pragma unroll
  for (int c = 0; c < 4; ++c) {
    int row = c * 64 + srow;
    int rw = (row < valid) ? row : 0;
    arow[c] = (size_t)(tok[row0 + rw] & 0xFFFF) * KDIM;
  }

  // chunk-XOR swizzle (involution): LDS chunk c holds logical chunk c^(row&7);
  // source pre-swizzled, LDS dest linear (wave-uniform base + lane*16).
  auto stage = [&](int buf, int kt) {
#pragma unroll
    for (int c = 0; c < 4; ++c) {
      int row = c * 64 + srow;
      int kc = (schunk ^ (row & 7)) << 3;
      __builtin_amdgcn_global_load_lds(
          (const __attribute__((address_space(1))) void*)(A + arow[c] + kt * 64 + kc),
          (__attribute__((address_space(3))) void*)(&As[buf][row * 64 + schunk * 8]), 16, 0, 0);
    }
#pragma unroll
    for (int c = 0; c < 4; ++c) {
      int row = c * 64 + srow;
      int kc = (schunk ^ (row & 7)) << 3;
      __builtin_amdgcn_global_load_lds(
          (const __attribute__((address_space(1))) void*)(Bb + (size_t)row * KDIM + kt * 64 + kc),
          (__attribute__((address_space(3))) void*)(&Bs[buf][row * 64 + schunk * 8]), 16, 0, 0);
    }
  };

  // acc[fn][fm]: D^T — lane holds token m = wr*128 + fm*16 + r,
  // cols n = bn0 + wc*64 + fn*16 + kq*4 + {0..3}.
  f32x4 acc[4][8] = {};

  stage(0, 0);
  asm volatile("s_waitcnt vmcnt(0)" ::: "memory");
  __builtin_amdgcn_s_barrier();

  int cur = 0;
  for (int kt = 0; kt < NKT; ++kt) {
    const bool more = (kt + 1 < NKT);
    if (more) stage(cur ^ 1, kt + 1);      // issue next-tile loads first
#pragma unroll
    for (int kh = 0; kh < 2; ++kh) {       // two K=32 halves of the BK=64 tile
      bf16x8 af[8], bfr[4];
      const int ck = kh * 4 + kq;
#pragma unroll
      for (int f = 0; f < 8; ++f) {
        int ra = wr * 128 + f * 16 + r;
        af[f] = *(const bf16x8*)(&As[cur][ra * 64 + ((ck ^ (ra & 7)) << 3)]);
      }
#pragma unroll
      for (int f = 0; f < 4; ++f) {
        int rb = wc * 64 + f * 16 + r;
        bfr[f] = *(const bf16x8*)(&Bs[cur][rb * 64 + ((ck ^ (rb & 7)) << 3)]);
      }
#pragma unroll
      for (int fm = 0; fm < 8; ++fm) {
#pragma unroll
        for (int fn = 0; fn < 4; ++fn) {
          acc[fn][fm] = __builtin_amdgcn_mfma_f32_16x16x32_bf16(bfr[fn], af[fm], acc[fn][fm], 0, 0, 0);
        }
      }
    }
    if (more) {
      asm volatile("s_waitcnt lgkmcnt(0)" ::: "memory");  // buf reads done
      asm volatile("s_waitcnt vmcnt(0)" ::: "memory");    // next tile landed
      __builtin_amdgcn_s_barrier();
      cur ^= 1;
    }
  }

  // epilogue: D^T — 4 consecutive cols per lane, ushort4 stores
#pragma unroll
  for (int fm = 0; fm < 8; ++fm) {
    int lr = wr * 128 + fm * 16 + r;
    if (lr < valid) {
      u16* hrow = Hout + (size_t)(row0 + lr) * EDIM;
#pragma unroll
      for (int fn = 0; fn < 4; ++fn) {
        int col0 = bn0 + wc * 64 + fn * 16 + kq * 4;
        float4 bv = *(const float4*)(bias + (size_t)e * EDIM + col0);
        float v0 = acc[fn][fm][0] + bv.x; v0 = v0 > 0.f ? v0 : 0.f;
        float v1 = acc[fn][fm][1] + bv.y; v1 = v1 > 0.f ? v1 : 0.f;
        float v2 = acc[fn][fm][2] + bv.z; v2 = v2 > 0.f ? v2 : 0.f;
        float v3 = acc[fn][fm][3] + bv.w; v3 = v3 > 0.f ? v3 : 0.f;
        ushort4 h = make_ushort4(f32_bf16(v0), f32_bf16(v1), f32_bf16(v2), f32_bf16(v3));
        *(ushort4*)(hrow + col0) = h;
      }
    }
  }
}

// ---------------- GEMM2 (round-5 verified config, unchanged) -----------------
template<int MODE, int SPLITK>
__global__ __launch_bounds__(256) void gemm_sparse(
    const u16* __restrict__ A, const u16* __restrict__ Wt,
    const int* __restrict__ nmtP, const int* __restrict__ mtE,
    const int* __restrict__ mtRow0, const int* __restrict__ mtValid,
    const int* __restrict__ tok,
    const float* __restrict__ bias, u16* __restrict__ Hout,
    float* __restrict__ Y0, float* __restrict__ Y1)
{
  constexpr int KDIM = (MODE == 1) ? HID : EDIM;
  constexpr int NDIM = (MODE == 1) ? EDIM : HID;
  constexpr int NT = NDIM / 128;
  constexpr int NK = KDIM / 32 / SPLITK;

  const int nwg = gridDim.x;
  const int q = nwg >> 3, rr8 = nwg & 7;
  const int xcd = blockIdx.x & 7, jj = blockIdx.x >> 3;
  int item = (xcd < rr8 ? xcd * (q + 1) : rr8 * (q + 1) + (xcd - rr8) * q) + jj;

  if (item >= nmtP[0] * NT * SPLITK) return;
  const int gmt = item / (NT * SPLITK);      // mt-major: nt fastest
  const int sk  = (item / NT) % SPLITK;
  const int nt  = item % NT;
  const int e = mtE[gmt], row0 = mtRow0[gmt], valid = mtValid[gmt];
  const int kbeg = sk * (KDIM / SPLITK);

  __shared__ __align__(16) u16 As[3][128 * 32];
  __shared__ __align__(16) u16 Bs[3][128 * 32];
  const int t = threadIdx.x;
  const int lane = t & 63;
  const int w = t >> 6;
  const int wr = w >> 1, wc = w & 1;
  const int bn0 = nt << 7;
  const int kq = lane >> 4;
  const int r  = lane & 15;

  const u16* Bb = Wt + ((size_t)e * NDIM + bn0) * KDIM;

  size_t arow[2];
  int srow[2];
#pragma unroll
  for (int c = 0; c < 2; ++c) {
    int idx = c * 256 + t;
    int row = idx >> 2;
    srow[c] = row;
    if (MODE == 1) {
      int rw = (row < valid) ? row : 0;
      arow[c] = (size_t)(tok[row0 + rw] & 0xFFFF) * KDIM;
    } else {
      arow[c] = (size_t)(row0 + row) * KDIM;
    }
  }

  auto stage = [&](int buf, int k0) {
#pragma unroll
    for (int c = 0; c < 2; ++c) {
      int idx = c * 256 + t;
      int row = idx >> 2;
      int kc  = (((idx & 3) ^ ((row >> 1) & 3))) << 3;
      __builtin_amdgcn_global_load_lds(
          (const __attribute__((address_space(1))) void*)(A + arow[c] + k0 + kc),
          (__attribute__((address_space(3))) void*)(&As[buf][idx * 8]), 16, 0, 0);
      __builtin_amdgcn_global_load_lds(
          (const __attribute__((address_space(1))) void*)(Bb + (size_t)srow[c] * KDIM + k0 + kc),
          (__attribute__((address_space(3))) void*)(&Bs[buf][idx * 8]), 16, 0, 0);
    }
  };

  f32x4 acc[4][4] = {};

  stage(0, kbeg);
  stage(1, kbeg + 32);
  int cb = 0, sb = 2;
  for (int ks = 0; ks < NK; ++ks) {
    if (ks + 1 < NK) asm volatile("s_waitcnt vmcnt(4)" ::: "memory");
    else             asm volatile("s_waitcnt vmcnt(0)" ::: "memory");
    __builtin_amdgcn_s_barrier();
    __builtin_amdgcn_sched_barrier(0);
    if (ks + 2 < NK) stage(sb, kbeg + (ks + 2) * 32);

    bf16x8 af[4], bfr[4];
#pragma unroll
    for (int f = 0; f < 4; ++f) {
      int ra = wr * 64 + f * 16 + r;
      af[f]  = *(const bf16x8*)(&As[cb][ra * 32 + ((kq ^ ((ra >> 1) & 3)) << 3)]);
      int rb = wc * 64 + f * 16 + r;
      bfr[f] = *(const bf16x8*)(&Bs[cb][rb * 32 + ((kq ^ ((rb >> 1) & 3)) << 3)]);
    }
    __builtin_amdgcn_s_setprio(1);
#pragma unroll
    for (int fm = 0; fm < 4; ++fm) {
#pragma unroll
      for (int fn = 0; fn < 4; ++fn) {
        acc[fn][fm] = __builtin_amdgcn_mfma_f32_16x16x32_bf16(bfr[fn], af[fm], acc[fn][fm], 0, 0, 0);
      }
    }
    __builtin_amdgcn_s_setprio(0);
    cb = (cb == 2) ? 0 : cb + 1;
    sb = (sb == 2) ? 0 : sb + 1;
  }

  if (MODE == 1) {
#pragma unroll
    for (int fm = 0; fm < 4; ++fm) {
      int lr = wr * 64 + fm * 16 + r;
      if (lr < valid) {
        u16* hrow = Hout + (size_t)(row0 + lr) * EDIM;
#pragma unroll
        for (int fn = 0; fn < 4; ++fn) {
          int col0 = bn0 + wc * 64 + fn * 16 + kq * 4;
          float4 bv = *(const float4*)(bias + (size_t)e * EDIM + col0);
          float v0 = acc[fn][fm][0] + bv.x; v0 = v0 > 0.f ? v0 : 0.f;
          float v1 = acc[fn][fm][1] + bv.y; v1 = v1 > 0.f ? v1 : 0.f;
          float v2 = acc[fn][fm][2] + bv.z; v2 = v2 > 0.f ? v2 : 0.f;
          float v3 = acc[fn][fm][3] + bv.w; v3 = v3 > 0.f ? v3 : 0.f;
          ushort4 h = make_ushort4(f32_bf16(v0), f32_bf16(v1), f32_bf16(v2), f32_bf16(v3));
          *(ushort4*)(hrow + col0) = h;
        }
      }
    }
  } else {
    float* Yb = (sk == 0) ? Y0 : Y1;
#pragma unroll
    for (int fm = 0; fm < 4; ++fm) {
      int lr = wr * 64 + fm * 16 + r;
      if (lr < valid) {
        int entry = tok[row0 + lr];
        int tt = entry & 0xFFFF, ss = entry >> 16;
        float* yrow = Yb + ((size_t)ss * NTOK + tt) * HID;
#pragma unroll
        for (int fn = 0; fn < 4; ++fn) {
          int col0 = bn0 + wc * 64 + fn * 16 + kq * 4;
          float4 o;
          if (sk == 0) {
            float4 bv = *(const float4*)(bias + (size_t)e * HID + col0);
            o.x = acc[fn][fm][0] + bv.x;
            o.y = acc[fn][fm][1] + bv.y;
            o.z = acc[fn][fm][2] + bv.z;
            o.w = acc[fn][fm][3] + bv.w;
          } else {
            o.x = acc[fn][fm][0];
            o.y = acc[fn][fm][1];
            o.z = acc[fn][fm][2];
            o.w = acc[fn][fm][3];
          }
          *(float4*)(yrow + col0) = o;
        }
      }
    }
  }
}

// ---------------- final combine ----------------
__global__ void final_kernel(const float* __restrict__ top2g,
                             const float* __restrict__ Ys0,
                             const float* __restrict__ Ys1,
                             float* __restrict__ out) {
  size_t idx4 = (size_t)blockIdx.x * 256 + threadIdx.x;
  size_t base = idx4 * 4;
  int t = (int)(base >> 10);
  float g0 = top2g[t * 2], g1 = top2g[t * 2 + 1];
  float4 a0 = *(const float4*)(Ys0 + base);
  float4 b0 = *(const float4*)(Ys1 + base);
  float4 a1 = *(const float4*)(Ys0 + (size_t)NTOK * HID + base);
  float4 b1 = *(const float4*)(Ys1 + (size_t)NTOK * HID + base);
  float4 o;
  o.x = g0 * (a0.x + b0.x) + g1 * (a1.x + b1.x);
  o.y = g0 * (a0.y + b0.y) + g1 * (a1.y + b1.y);
  o.z = g0 * (a0.z + b0.z) + g1 * (a1.z + b1.z);
  o.w = g0 * (a0.w + b0.w) + g1 * (a1.w + b1.w);
  *(float4*)(out + base) = o;
}

// ---------------- dense fallback (round 1) ----------------
__global__ void init_out_kernel(const float* __restrict__ combine,
                                const float* __restrict__ b2,
                                float* __restrict__ out) {
  size_t idx = (size_t)blockIdx.x * 256 + threadIdx.x;
  int i = (int)(idx >> 10), j = (int)(idx & 1023);
  float v = 0.f;
#pragma unroll
  for (int e = 0; e < NEXP; ++e) v += combine[(size_t)i * NEXP + e] * b2[e * HID + j];
  out[idx] = v;
}

template<int MODE>
__global__ __launch_bounds__(256) void gemm_kernel(
    const u16* __restrict__ A, const u16* __restrict__ BT,
    int M, int N, int K,
    const float* __restrict__ bias, u16* __restrict__ Hout,
    const float* __restrict__ combine, int expert, float* __restrict__ Out)
{
  __shared__ __align__(16) u16 As[128 * 32];
  __shared__ __align__(16) u16 Bs[128 * 32];
  const int t = threadIdx.x;
  const int lane = t & 63;
  const int w = t >> 6;
  const int wr = w >> 1, wc = w & 1;
  const int nbn = N >> 7;
  const int bm0 = (int)(blockIdx.x / nbn) << 7;
  const int bn0 = (int)(blockIdx.x % nbn) << 7;
  const int kq = lane >> 4;
  const int r  = lane & 15;
  f32x4 acc[4][4] = {};
  const u16* Ab = A + (size_t)bm0 * K;
  const u16* Bb = BT + (size_t)bn0 * K;
  for (int k0 = 0; k0 < K; k0 += 32) {
    __syncthreads();
#pragma unroll
    for (int c = 0; c < 2; ++c) {
      int idx = c * 256 + t;
      int row = idx >> 2;
      int kc  = (idx & 3) << 3;
      __builtin_amdgcn_global_load_lds(
          (const __attribute__((address_space(1))) void*)(Ab + (size_t)row * K + k0 + kc),
          (__attribute__((address_space(3))) void*)(As + idx * 8), 16, 0, 0);
      __builtin_amdgcn_global_load_lds(
          (const __attribute__((address_space(1))) void*)(Bb + (size_t)row * K + k0 + kc),
          (__attribute__((address_space(3))) void*)(Bs + idx * 8), 16, 0, 0);
    }
    __syncthreads();
    bf16x8 af[4], bfr[4];
#pragma unroll
    for (int f = 0; f < 4; ++f) {
      af[f]  = *(const bf16x8*)(As + (wr * 64 + f * 16 + r) * 32 + kq * 8);
      bfr[f] = *(const bf16x8*)(Bs + (wc * 64 + f * 16 + r) * 32 + kq * 8);
    }
#pragma unroll
    for (int fm = 0; fm < 4; ++fm) {
#pragma unroll
      for (int fn = 0; fn < 4; ++fn) {
        acc[fm][fn] = __builtin_amdgcn_mfma_f32_16x16x32_bf16(af[fm], bfr[fn], acc[fm][fn], 0, 0, 0);
      }
    }
  }
  if (MODE == 1) {
#pragma unroll
    for (int fn = 0; fn < 4; ++fn) {
      int col = bn0 + wc * 64 + fn * 16 + r;
      float bv = bias[col];
#pragma unroll
      for (int fm = 0; fm < 4; ++fm) {
#pragma unroll
        for (int j = 0; j < 4; ++j) {
          int row = bm0 + wr * 64 + fm * 16 + kq * 4 + j;
          float v = acc[fm][fn][j] + bv;
          v = v > 0.f ? v : 0.f;
          Hout[(size_t)row * N + col] = f32_bf16(v);
        }
      }
    }
  } else {
#pragma unroll
    for (int fm = 0; fm < 4; ++fm) {
      float cg[4];
#pragma unroll
      for (int j = 0; j < 4; ++j) {
        int row = bm0 + wr * 64 + fm * 16 + kq * 4 + j;
        cg[j] = combine[(size_t)row * NEXP + expert];
      }
#pragma unroll
      for (int fn = 0; fn < 4; ++fn) {
        int col = bn0 + wc * 64 + fn * 16 + r;
#pragma unroll
        for (int j = 0; j < 4; ++j) {
          int row = bm0 + wr * 64 + fm * 16 + kq * 4 + j;
          Out[(size_t)row * N + col] += cg[j] * acc[fm][fn][j];
        }
      }
    }
  }
}

// ---------------- launch ----------------
extern "C" void kernel_launch(void* const* d_in, const int* in_sizes, int n_in,
                              void* d_out, int out_size, void* d_ws, size_t ws_size,
                              hipStream_t stream) {
  (void)in_sizes; (void)n_in; (void)out_size;
  const float* x  = (const float*)d_in[0];
  const float* Wg = (const float*)d_in[1];
  const float* bg = (const float*)d_in[2];
  const float* W1 = (const float*)d_in[3];
  const float* b1 = (const float*)d_in[4];
  const float* W2 = (const float*)d_in[5];
  const float* b2 = (const float*)d_in[6];
  float* out = (float*)d_out;

  char* ws = (char*)d_ws;
  float* counts   = (float*)(ws);
  int*   icnt     = (int*)(ws + 64);
  int*   nmtP     = (int*)(ws + 256);
  int*   nmtP2    = (int*)(ws + 384);
  int*   mtE      = (int*)(ws + 512);
  int*   mtRow0   = (int*)(ws + 1024);
  int*   mtValid  = (int*)(ws + 1536);
  int*   mtE2     = (int*)(ws + 2048);
  int*   mtRow02  = (int*)(ws + 2304);
  int*   mtValid2 = (int*)(ws + 2560);
  int*   top2idx  = (int*)(ws + 4096);
  float* top2g    = (float*)(ws + 36864);
  int*   tok      = (int*)(ws + 69632);
  float* combine  = (float*)(ws + 131072);

  const size_t MB = 1024 * 1024;
  u16* xbf = (u16*)(ws + 1 * MB);           // 8 MB

  const size_t REQ = 241 * MB;
  bool sparse = ws_size >= REQ;

  hipMemsetAsync(ws, 0, 1024, stream);
  gate_kernel<<<NTOK / 4, 256, 0, stream>>>(x, Wg, bg, combine, counts, icnt,
                                            top2idx, top2g, xbf);

  if (sparse) {
    u16* w1tA    = (u16*)(ws + 9 * MB);       // 64 MB (dead after GEMM1)
    u16* w2tA    = (u16*)(ws + 73 * MB);      // 64 MB
    u16* H       = (u16*)(ws + 137 * MB);     // 72 MB
    float* Ys0   = (float*)(ws + 209 * MB);   // 32 MB
    float* Ys1   = (float*)(ws + 9 * MB);     // reuse w1tA region: 32 MB

    cvtT_kernel<<<dim3(EDIM / 64, HID / 64, NEXP), 256, 0, stream>>>(W1, w1tA, HID, EDIM);
    cvtT_kernel<<<dim3(HID / 64, EDIM / 64, NEXP), 256, 0, stream>>>(W2, w2tA, EDIM, HID);
    route_kernel<<<1, 256, 0, stream>>>(icnt, counts, top2idx, nmtP, mtE, mtRow0,
                                        mtValid, nmtP2, mtE2, mtRow02, mtValid2,
                                        tok, out + (size_t)NTOK * HID);

    gemm1_256<<<MAXMT2 * (EDIM / 256), 512, 0, stream>>>(
        xbf, w1tA, nmtP2, mtE2, mtRow02, mtValid2, tok, b1, H);
    gemm_sparse<2, 2><<<MAXMT * (HID / 128) * 2, 256, 0, stream>>>(
        H, w2tA, nmtP, mtE, mtRow0, mtValid, tok, b2, nullptr, Ys0, Ys1);
    final_kernel<<<(NTOK * HID / 4) / 256, 256, 0, stream>>>(top2g, Ys0, Ys1, out);
  } else {
    // dense fallback (round-1 path)
    u16* w1t = (u16*)(ws + 9 * MB);
    u16* w2t = (u16*)(ws + 17 * MB);
    u16* H   = (u16*)(ws + 25 * MB);
    aux_kernel<<<1, 1, 0, stream>>>(counts, out + (size_t)NTOK * HID);
    init_out_kernel<<<(NTOK * HID) / 256, 256, 0, stream>>>(combine, b2, out);
    for (int e = 0; e < NEXP; ++e) {
      cvtT_kernel<<<dim3(EDIM / 64, HID / 64, 1), 256, 0, stream>>>(
          W1 + (size_t)e * HID * EDIM, w1t, HID, EDIM);
      gemm_kernel<1><<<(NTOK / 128) * (EDIM / 128), 256, 0, stream>>>(
          xbf, w1t, NTOK, EDIM, HID, b1 + (size_t)e * EDIM, H, nullptr, 0, nullptr);
      cvtT_kernel<<<dim3(HID / 64, EDIM / 64, 1), 256, 0, stream>>>(
          W2 + (size_t)e * EDIM * HID, w2t, EDIM, HID);
      gemm_kernel<2><<<(NTOK / 128) * (HID / 128), 256, 0, stream>>>(
          H, w2t, NTOK, HID, EDIM, nullptr, nullptr, combine, e, out);
    }
  }
}

// Round 12
// 464.173 us; speedup vs baseline: 1.0592x; 1.0592x over previous
//
#include <hip/hip_runtime.h>

// MoE FFN (8 experts, top-2) — round 12: round-10 verified state (3-deep
// counted-vmcnt 128x128 GEMMs, chunk-XOR swizzle, setprio, D^T epilogue,
// GEMM2 split-K=2, mt-major + bijective XCD swizzle, gate+cvt fused,
// route merged) + single fused cvtT dispatch for W1+W2.

typedef unsigned short u16;
typedef __bf16 bf16x8 __attribute__((ext_vector_type(8)));
typedef float  f32x4  __attribute__((ext_vector_type(4)));

#define NTOK 4096
#define HID  1024
#define EDIM 4096
#define NEXP 8
#define MAXMT 72   // sum ceil(cnt_e/128) <= 8192/128 + 8

__device__ __forceinline__ u16 f32_bf16(float f) {
  unsigned int u = __float_as_uint(f);
  u += 0x7FFFu + ((u >> 16) & 1u);   // RNE
  return (u16)(u >> 16);
}

// ---------------- gating: one wave per token (+ fused x->bf16) ----------------
__global__ void gate_kernel(const float* __restrict__ x,
                            const float* __restrict__ Wg,
                            const float* __restrict__ bg,
                            float* __restrict__ combine,
                            float* __restrict__ counts,
                            int* __restrict__ icnt,
                            int* __restrict__ top2idx,
                            float* __restrict__ top2g,
                            u16* __restrict__ xbf) {
  __shared__ float lc[NEXP];
  int t = threadIdx.x;
  if (t < NEXP) lc[t] = 0.f;
  __syncthreads();
  int token = blockIdx.x * 4 + (t >> 6);
  int lane = t & 63;
  float s[NEXP] = {};
  const float* xr = x + (size_t)token * HID;
  u16* xb = xbf + (size_t)token * HID;
  for (int h = lane; h < HID; h += 64) {
    float xv = xr[h];
    xb[h] = f32_bf16(xv);                       // fused conversion
    const float* wrow = Wg + (size_t)h * NEXP;
#pragma unroll
    for (int e = 0; e < NEXP; ++e) s[e] += xv * wrow[e];
  }
#pragma unroll
  for (int off = 32; off > 0; off >>= 1) {
#pragma unroll
    for (int e = 0; e < NEXP; ++e) s[e] += __shfl_xor(s[e], off);
  }
  float m = -1e30f;
#pragma unroll
  for (int e = 0; e < NEXP; ++e) { s[e] += bg[e]; m = fmaxf(m, s[e]); }
  float p[NEXP]; float sum = 0.f;
#pragma unroll
  for (int e = 0; e < NEXP; ++e) { p[e] = expf(s[e] - m); sum += p[e]; }
  float inv = 1.f / sum;
#pragma unroll
  for (int e = 0; e < NEXP; ++e) p[e] *= inv;
  int i1 = 0; float g1 = p[0];
#pragma unroll
  for (int e = 1; e < NEXP; ++e) if (p[e] > g1) { g1 = p[e]; i1 = e; }
  int i2 = -1; float g2 = -1.f;
#pragma unroll
  for (int e = 0; e < NEXP; ++e) if (e != i1 && p[e] > g2) { g2 = p[e]; i2 = e; }
  float ginv = 1.f / (g1 + g2);
  if (lane == 0) {
#pragma unroll
    for (int e = 0; e < NEXP; ++e) {
      float c = (e == i1) ? g1 * ginv : (e == i2) ? g2 * ginv : 0.f;
      combine[(size_t)token * NEXP + e] = c;
      atomicAdd(&lc[e], p[e]);
    }
    top2idx[token * 2] = i1; top2idx[token * 2 + 1] = i2;
    top2g[token * 2] = g1 * ginv; top2g[token * 2 + 1] = g2 * ginv;
    atomicAdd(&icnt[i1], 1); atomicAdd(&icnt[i2], 1);
  }
  __syncthreads();
  if (t < NEXP) atomicAdd(&counts[t], lc[t]);
}

__global__ void aux_kernel(const float* __restrict__ counts, float* __restrict__ aux_out) {
  float s = 0.f;
#pragma unroll
  for (int e = 0; e < NEXP; ++e) s += counts[e];
  float a = 0.f;
#pragma unroll
  for (int e = 0; e < NEXP; ++e) a += (counts[e] / s) * (counts[e] / (float)NTOK);
  aux_out[0] = (float)NEXP * a;
}

// ---------------- routing: tiles + aux + token scatter, one block ------------
__global__ void route_kernel(const int* __restrict__ icnt,
                             const float* __restrict__ counts,
                             const int* __restrict__ top2idx,
                             int* __restrict__ nmtP,
                             int* __restrict__ mtE, int* __restrict__ mtRow0,
                             int* __restrict__ mtValid,
                             int* __restrict__ tok,
                             float* __restrict__ aux_out) {
  __shared__ int l_off[NEXP];
  __shared__ int l_cur[NEXP];
  int t = threadIdx.x;
  if (t == 0) {
    int s = 0, nm = 0;
    for (int e = 0; e < NEXP; ++e) {
      l_off[e] = s; l_cur[e] = 0;
      int c = icnt[e];
      int tiles = (c + 127) >> 7;
      for (int mt = 0; mt < tiles; ++mt) {
        mtE[nm] = e; mtRow0[nm] = s + (mt << 7);
        int v = c - (mt << 7); mtValid[nm] = v > 128 ? 128 : v;
        nm++;
      }
      s += c;
    }
    nmtP[0] = nm;
    float fs = 0.f;
    for (int e = 0; e < NEXP; ++e) fs += counts[e];
    float a = 0.f;
    for (int e = 0; e < NEXP; ++e) a += (counts[e] / fs) * (counts[e] / (float)NTOK);
    aux_out[0] = (float)NEXP * a;
  }
  __syncthreads();
  for (int i = t; i < NTOK * 2; i += 256) {
    int e = top2idx[i];
    int pos = atomicAdd(&l_cur[e], 1);
    tok[l_off[e] + pos] = (i >> 1) | ((i & 1) << 16);
  }
}

// ---------------- fused W1+W2 f32 [R][C] -> bf16 transposed [C][R] ----------
// 1D grid: blocks [0, 8192) -> W1 (R=HID, C=EDIM), [8192, 16384) -> W2.
__global__ __launch_bounds__(256) void cvtT_all_kernel(const float* __restrict__ W1,
                                                       u16* __restrict__ W1T,
                                                       const float* __restrict__ W2,
                                                       u16* __restrict__ W2T) {
  __shared__ u16 tile[64][66];
  int t = threadIdx.x;
  int bid = blockIdx.x;
  const float* W; u16* WT; int R, C, e, gx, gy;
  if (bid < 8192) {
    W = W1; WT = W1T; R = HID; C = EDIM;
    e = bid >> 10; int rem = bid & 1023;
    gx = rem & 63;  gy = rem >> 6;       // 64 x 16
  } else {
    W = W2; WT = W2T; R = EDIM; C = HID;
    int b = bid - 8192;
    e = b >> 10; int rem = b & 1023;
    gx = rem & 15;  gy = rem >> 4;       // 16 x 64
  }
  size_t eoff = (size_t)e * R * C;
  int c0 = gx * 64, r0 = gy * 64;
  const float* Wp = W + eoff + (size_t)r0 * C + c0;
  u16* WTp = WT + eoff + (size_t)c0 * R + r0;
#pragma unroll
  for (int p = 0; p < 4; ++p) {
    int idx = p * 256 + t;
    int row = idx >> 4;          // 0..63
    int col = (idx & 15) * 4;    // 0..60
    float4 v = *(const float4*)(Wp + (size_t)row * C + col);
    tile[row][col + 0] = f32_bf16(v.x);
    tile[row][col + 1] = f32_bf16(v.y);
    tile[row][col + 2] = f32_bf16(v.z);
    tile[row][col + 3] = f32_bf16(v.w);
  }
  __syncthreads();
#pragma unroll
  for (int p = 0; p < 4; ++p) {
    int idx = p * 256 + t;
    int oc = idx >> 4;           // output row (= source col), 0..63
    int orow = (idx & 15) * 4;   // position along R, 0..60
    ushort4 o;
    o.x = tile[orow + 0][oc];
    o.y = tile[orow + 1][oc];
    o.z = tile[orow + 2][oc];
    o.w = tile[orow + 3][oc];
    *(ushort4*)(WTp + (size_t)oc * R + orow) = o;
  }
}

// single-expert cvtT for the dense fallback path
__global__ __launch_bounds__(256) void cvtT_kernel(const float* __restrict__ W,
                                                   u16* __restrict__ WT, int R, int C) {
  __shared__ u16 tile[64][66];
  int t = threadIdx.x;
  int c0 = blockIdx.x * 64, r0 = blockIdx.y * 64;
  const float* Wp = W + (size_t)r0 * C + c0;
  u16* WTp = WT + (size_t)c0 * R + r0;
#pragma unroll
  for (int p = 0; p < 4; ++p) {
    int idx = p * 256 + t;
    int row = idx >> 4;
    int col = (idx & 15) * 4;
    float4 v = *(const float4*)(Wp + (size_t)row * C + col);
    tile[row][col + 0] = f32_bf16(v.x);
    tile[row][col + 1] = f32_bf16(v.y);
    tile[row][col + 2] = f32_bf16(v.z);
    tile[row][col + 3] = f32_bf16(v.w);
  }
  __syncthreads();
#pragma unroll
  for (int p = 0; p < 4; ++p) {
    int idx = p * 256 + t;
    int oc = idx >> 4;
    int orow = (idx & 15) * 4;
    ushort4 o;
    o.x = tile[orow + 0][oc];
    o.y = tile[orow + 1][oc];
    o.z = tile[orow + 2][oc];
    o.w = tile[orow + 3][oc];
    *(ushort4*)(WTp + (size_t)oc * R + orow) = o;
  }
}

// ---------------- sparse persistent GEMM (round-5 verified config) -----------
// 128x128 tile, 4 waves, 3-deep counted-vmcnt pipeline, chunk-XOR swizzle,
// setprio, D^T epilogue. mt-major item order (nt fastest: A-panel L2 reuse).
// MODE 1: A = xbf (gathered rows), K=HID; H[row][n] = bf16(relu(acc+b1)).
// MODE 2: A = H (contiguous rows), K=EDIM/SPLITK; split 0 adds b2.
template<int MODE, int SPLITK>
__global__ __launch_bounds__(256) void gemm_sparse(
    const u16* __restrict__ A, const u16* __restrict__ Wt,
    const int* __restrict__ nmtP, const int* __restrict__ mtE,
    const int* __restrict__ mtRow0, const int* __restrict__ mtValid,
    const int* __restrict__ tok,
    const float* __restrict__ bias, u16* __restrict__ Hout,
    float* __restrict__ Y0, float* __restrict__ Y1)
{
  constexpr int KDIM = (MODE == 1) ? HID : EDIM;
  constexpr int NDIM = (MODE == 1) ? EDIM : HID;
  constexpr int NT = NDIM / 128;
  constexpr int NK = KDIM / 32 / SPLITK;

  // bijective XCD swizzle (m204): consecutive items land on one XCD
  const int nwg = gridDim.x;
  const int q = nwg >> 3, rr8 = nwg & 7;
  const int xcd = blockIdx.x & 7, jj = blockIdx.x >> 3;
  int item = (xcd < rr8 ? xcd * (q + 1) : rr8 * (q + 1) + (xcd - rr8) * q) + jj;

  if (item >= nmtP[0] * NT * SPLITK) return;
  const int gmt = item / (NT * SPLITK);      // mt-major: nt fastest
  const int sk  = (item / NT) % SPLITK;
  const int nt  = item % NT;
  const int e = mtE[gmt], row0 = mtRow0[gmt], valid = mtValid[gmt];
  const int kbeg = sk * (KDIM / SPLITK);

  __shared__ __align__(16) u16 As[3][128 * 32];
  __shared__ __align__(16) u16 Bs[3][128 * 32];
  const int t = threadIdx.x;
  const int lane = t & 63;
  const int w = t >> 6;
  const int wr = w >> 1, wc = w & 1;
  const int bn0 = nt << 7;
  const int kq = lane >> 4;   // 0..3 (16B chunk within 64B row)
  const int r  = lane & 15;

  const u16* Bb = Wt + ((size_t)e * NDIM + bn0) * KDIM;

  size_t arow[2];
  int srow[2];
#pragma unroll
  for (int c = 0; c < 2; ++c) {
    int idx = c * 256 + t;
    int row = idx >> 2;
    srow[c] = row;
    if (MODE == 1) {
      int rw = (row < valid) ? row : 0;
      arow[c] = (size_t)(tok[row0 + rw] & 0xFFFF) * KDIM;
    } else {
      arow[c] = (size_t)(row0 + row) * KDIM;
    }
  }

  // Source-side chunk swizzle (involution): LDS chunk c holds logical chunk
  // c ^ ((row>>1)&3); read applies the same XOR -> 2-way banks (free).
  auto stage = [&](int buf, int k0) {
#pragma unroll
    for (int c = 0; c < 2; ++c) {
      int idx = c * 256 + t;
      int row = idx >> 2;
      int kc  = (((idx & 3) ^ ((row >> 1) & 3))) << 3;
      __builtin_amdgcn_global_load_lds(
          (const __attribute__((address_space(1))) void*)(A + arow[c] + k0 + kc),
          (__attribute__((address_space(3))) void*)(&As[buf][idx * 8]), 16, 0, 0);
      __builtin_amdgcn_global_load_lds(
          (const __attribute__((address_space(1))) void*)(Bb + (size_t)srow[c] * KDIM + k0 + kc),
          (__attribute__((address_space(3))) void*)(&Bs[buf][idx * 8]), 16, 0, 0);
    }
  };

  // acc[fn][fm]: D^T fragments — lane holds token m = fm*16+r,
  // cols n = fn*16 + kq*4 + {0..3} (4 consecutive).
  f32x4 acc[4][4] = {};

  // 3-deep pipeline: tile t staged at iter t-2 into buf t%3. Per-iter:
  // counted vmcnt (t+1's 4 loads stay in flight) -> barrier -> stage t+2 ->
  // ds_read t -> MFMA. Buf re-stage race-safe (readers done before barrier).
  stage(0, kbeg);
  stage(1, kbeg + 32);
  int cb = 0, sb = 2;
  for (int ks = 0; ks < NK; ++ks) {
    if (ks + 1 < NK) asm volatile("s_waitcnt vmcnt(4)" ::: "memory");
    else             asm volatile("s_waitcnt vmcnt(0)" ::: "memory");
    __builtin_amdgcn_s_barrier();
    __builtin_amdgcn_sched_barrier(0);
    if (ks + 2 < NK) stage(sb, kbeg + (ks + 2) * 32);

    bf16x8 af[4], bfr[4];
#pragma unroll
    for (int f = 0; f < 4; ++f) {
      int ra = wr * 64 + f * 16 + r;
      af[f]  = *(const bf16x8*)(&As[cb][ra * 32 + ((kq ^ ((ra >> 1) & 3)) << 3)]);
      int rb = wc * 64 + f * 16 + r;
      bfr[f] = *(const bf16x8*)(&Bs[cb][rb * 32 + ((kq ^ ((rb >> 1) & 3)) << 3)]);
    }
    __builtin_amdgcn_s_setprio(1);
#pragma unroll
    for (int fm = 0; fm < 4; ++fm) {
#pragma unroll
      for (int fn = 0; fn < 4; ++fn) {
        acc[fn][fm] = __builtin_amdgcn_mfma_f32_16x16x32_bf16(bfr[fn], af[fm], acc[fn][fm], 0, 0, 0);
      }
    }
    __builtin_amdgcn_s_setprio(0);
    cb = (cb == 2) ? 0 : cb + 1;
    sb = (sb == 2) ? 0 : sb + 1;
  }

  if (MODE == 1) {
#pragma unroll
    for (int fm = 0; fm < 4; ++fm) {
      int lr = wr * 64 + fm * 16 + r;
      if (lr < valid) {
        u16* hrow = Hout + (size_t)(row0 + lr) * EDIM;
#pragma unroll
        for (int fn = 0; fn < 4; ++fn) {
          int col0 = bn0 + wc * 64 + fn * 16 + kq * 4;
          float4 bv = *(const float4*)(bias + (size_t)e * EDIM + col0);
          float v0 = acc[fn][fm][0] + bv.x; v0 = v0 > 0.f ? v0 : 0.f;
          float v1 = acc[fn][fm][1] + bv.y; v1 = v1 > 0.f ? v1 : 0.f;
          float v2 = acc[fn][fm][2] + bv.z; v2 = v2 > 0.f ? v2 : 0.f;
          float v3 = acc[fn][fm][3] + bv.w; v3 = v3 > 0.f ? v3 : 0.f;
          ushort4 h = make_ushort4(f32_bf16(v0), f32_bf16(v1), f32_bf16(v2), f32_bf16(v3));
          *(ushort4*)(hrow + col0) = h;
        }
      }
    }
  } else {
    float* Yb = (sk == 0) ? Y0 : Y1;
#pragma unroll
    for (int fm = 0; fm < 4; ++fm) {
      int lr = wr * 64 + fm * 16 + r;
      if (lr < valid) {
        int entry = tok[row0 + lr];
        int tt = entry & 0xFFFF, ss = entry >> 16;
        float* yrow = Yb + ((size_t)ss * NTOK + tt) * HID;
#pragma unroll
        for (int fn = 0; fn < 4; ++fn) {
          int col0 = bn0 + wc * 64 + fn * 16 + kq * 4;
          float4 o;
          if (sk == 0) {
            float4 bv = *(const float4*)(bias + (size_t)e * HID + col0);
            o.x = acc[fn][fm][0] + bv.x;
            o.y = acc[fn][fm][1] + bv.y;
            o.z = acc[fn][fm][2] + bv.z;
            o.w = acc[fn][fm][3] + bv.w;
          } else {
            o.x = acc[fn][fm][0];
            o.y = acc[fn][fm][1];
            o.z = acc[fn][fm][2];
            o.w = acc[fn][fm][3];
          }
          *(float4*)(yrow + col0) = o;
        }
      }
    }
  }
}

// ---------------- final combine: out = g0*(Y0s0+Y0s1) + g1*(Y1s0+Y1s1) -------
__global__ void final_kernel(const float* __restrict__ top2g,
                             const float* __restrict__ Ys0,
                             const float* __restrict__ Ys1,
                             float* __restrict__ out) {
  size_t idx4 = (size_t)blockIdx.x * 256 + threadIdx.x;
  size_t base = idx4 * 4;
  int t = (int)(base >> 10);
  float g0 = top2g[t * 2], g1 = top2g[t * 2 + 1];
  float4 a0 = *(const float4*)(Ys0 + base);
  float4 b0 = *(const float4*)(Ys1 + base);
  float4 a1 = *(const float4*)(Ys0 + (size_t)NTOK * HID + base);
  float4 b1 = *(const float4*)(Ys1 + (size_t)NTOK * HID + base);
  float4 o;
  o.x = g0 * (a0.x + b0.x) + g1 * (a1.x + b1.x);
  o.y = g0 * (a0.y + b0.y) + g1 * (a1.y + b1.y);
  o.z = g0 * (a0.z + b0.z) + g1 * (a1.z + b1.z);
  o.w = g0 * (a0.w + b0.w) + g1 * (a1.w + b1.w);
  *(float4*)(out + base) = o;
}

// ---------------- dense fallback GEMM (round 1) ----------------
__global__ void init_out_kernel(const float* __restrict__ combine,
                                const float* __restrict__ b2,
                                float* __restrict__ out) {
  size_t idx = (size_t)blockIdx.x * 256 + threadIdx.x;
  int i = (int)(idx >> 10), j = (int)(idx & 1023);
  float v = 0.f;
#pragma unroll
  for (int e = 0; e < NEXP; ++e) v += combine[(size_t)i * NEXP + e] * b2[e * HID + j];
  out[idx] = v;
}

template<int MODE>
__global__ __launch_bounds__(256) void gemm_kernel(
    const u16* __restrict__ A, const u16* __restrict__ BT,
    int M, int N, int K,
    const float* __restrict__ bias, u16* __restrict__ Hout,
    const float* __restrict__ combine, int expert, float* __restrict__ Out)
{
  __shared__ __align__(16) u16 As[128 * 32];
  __shared__ __align__(16) u16 Bs[128 * 32];
  const int t = threadIdx.x;
  const int lane = t & 63;
  const int w = t >> 6;
  const int wr = w >> 1, wc = w & 1;
  const int nbn = N >> 7;
  const int bm0 = (int)(blockIdx.x / nbn) << 7;
  const int bn0 = (int)(blockIdx.x % nbn) << 7;
  const int kq = lane >> 4;
  const int r  = lane & 15;
  f32x4 acc[4][4] = {};
  const u16* Ab = A + (size_t)bm0 * K;
  const u16* Bb = BT + (size_t)bn0 * K;
  for (int k0 = 0; k0 < K; k0 += 32) {
    __syncthreads();
#pragma unroll
    for (int c = 0; c < 2; ++c) {
      int idx = c * 256 + t;
      int row = idx >> 2;
      int kc  = (idx & 3) << 3;
      __builtin_amdgcn_global_load_lds(
          (const __attribute__((address_space(1))) void*)(Ab + (size_t)row * K + k0 + kc),
          (__attribute__((address_space(3))) void*)(As + idx * 8), 16, 0, 0);
      __builtin_amdgcn_global_load_lds(
          (const __attribute__((address_space(1))) void*)(Bb + (size_t)row * K + k0 + kc),
          (__attribute__((address_space(3))) void*)(Bs + idx * 8), 16, 0, 0);
    }
    __syncthreads();
    bf16x8 af[4], bfr[4];
#pragma unroll
    for (int f = 0; f < 4; ++f) {
      af[f]  = *(const bf16x8*)(As + (wr * 64 + f * 16 + r) * 32 + kq * 8);
      bfr[f] = *(const bf16x8*)(Bs + (wc * 64 + f * 16 + r) * 32 + kq * 8);
    }
#pragma unroll
    for (int fm = 0; fm < 4; ++fm) {
#pragma unroll
      for (int fn = 0; fn < 4; ++fn) {
        acc[fm][fn] = __builtin_amdgcn_mfma_f32_16x16x32_bf16(af[fm], bfr[fn], acc[fm][fn], 0, 0, 0);
      }
    }
  }
  if (MODE == 1) {
#pragma unroll
    for (int fn = 0; fn < 4; ++fn) {
      int col = bn0 + wc * 64 + fn * 16 + r;
      float bv = bias[col];
#pragma unroll
      for (int fm = 0; fm < 4; ++fm) {
#pragma unroll
        for (int j = 0; j < 4; ++j) {
          int row = bm0 + wr * 64 + fm * 16 + kq * 4 + j;
          float v = acc[fm][fn][j] + bv;
          v = v > 0.f ? v : 0.f;
          Hout[(size_t)row * N + col] = f32_bf16(v);
        }
      }
    }
  } else {
#pragma unroll
    for (int fm = 0; fm < 4; ++fm) {
      float cg[4];
#pragma unroll
      for (int j = 0; j < 4; ++j) {
        int row = bm0 + wr * 64 + fm * 16 + kq * 4 + j;
        cg[j] = combine[(size_t)row * NEXP + expert];
      }
#pragma unroll
      for (int fn = 0; fn < 4; ++fn) {
        int col = bn0 + wc * 64 + fn * 16 + r;
#pragma unroll
        for (int j = 0; j < 4; ++j) {
          int row = bm0 + wr * 64 + fm * 16 + kq * 4 + j;
          Out[(size_t)row * N + col] += cg[j] * acc[fm][fn][j];
        }
      }
    }
  }
}

// ---------------- launch ----------------
extern "C" void kernel_launch(void* const* d_in, const int* in_sizes, int n_in,
                              void* d_out, int out_size, void* d_ws, size_t ws_size,
                              hipStream_t stream) {
  (void)in_sizes; (void)n_in; (void)out_size;
  const float* x  = (const float*)d_in[0];
  const float* Wg = (const float*)d_in[1];
  const float* bg = (const float*)d_in[2];
  const float* W1 = (const float*)d_in[3];
  const float* b1 = (const float*)d_in[4];
  const float* W2 = (const float*)d_in[5];
  const float* b2 = (const float*)d_in[6];
  float* out = (float*)d_out;

  char* ws = (char*)d_ws;
  float* counts  = (float*)(ws);
  int*   icnt    = (int*)(ws + 64);
  int*   nmtP    = (int*)(ws + 256);
  int*   mtE     = (int*)(ws + 512);
  int*   mtRow0  = (int*)(ws + 1024);
  int*   mtValid = (int*)(ws + 1536);
  int*   top2idx = (int*)(ws + 4096);
  float* top2g   = (float*)(ws + 36864);
  int*   tok     = (int*)(ws + 69632);
  float* combine = (float*)(ws + 131072);

  const size_t MB = 1024 * 1024;
  u16* xbf = (u16*)(ws + 1 * MB);           // 8 MB

  const size_t REQ = 241 * MB;
  bool sparse = ws_size >= REQ;

  hipMemsetAsync(ws, 0, 1024, stream);
  gate_kernel<<<NTOK / 4, 256, 0, stream>>>(x, Wg, bg, combine, counts, icnt,
                                            top2idx, top2g, xbf);

  if (sparse) {
    u16* w1tA    = (u16*)(ws + 9 * MB);       // 64 MB (dead after GEMM1)
    u16* w2tA    = (u16*)(ws + 73 * MB);      // 64 MB
    u16* H       = (u16*)(ws + 137 * MB);     // 72 MB
    float* Ys0   = (float*)(ws + 209 * MB);   // 32 MB: [2][NTOK][HID]
    float* Ys1   = (float*)(ws + 9 * MB);     // reuse w1tA region: 32 MB

    cvtT_all_kernel<<<16384, 256, 0, stream>>>(W1, w1tA, W2, w2tA);
    route_kernel<<<1, 256, 0, stream>>>(icnt, counts, top2idx, nmtP, mtE, mtRow0,
                                        mtValid, tok, out + (size_t)NTOK * HID);

    gemm_sparse<1, 1><<<MAXMT * (EDIM / 128), 256, 0, stream>>>(
        xbf, w1tA, nmtP, mtE, mtRow0, mtValid, tok, b1, H, nullptr, nullptr);
    gemm_sparse<2, 2><<<MAXMT * (HID / 128) * 2, 256, 0, stream>>>(
        H, w2tA, nmtP, mtE, mtRow0, mtValid, tok, b2, nullptr, Ys0, Ys1);
    final_kernel<<<(NTOK * HID / 4) / 256, 256, 0, stream>>>(top2g, Ys0, Ys1, out);
  } else {
    // dense fallback (round-1 path)
    u16* w1t = (u16*)(ws + 9 * MB);
    u16* w2t = (u16*)(ws + 17 * MB);
    u16* H   = (u16*)(ws + 25 * MB);
    aux_kernel<<<1, 1, 0, stream>>>(counts, out + (size_t)NTOK * HID);
    init_out_kernel<<<(NTOK * HID) / 256, 256, 0, stream>>>(combine, b2, out);
    for (int e = 0; e < NEXP; ++e) {
      cvtT_kernel<<<dim3(EDIM / 64, HID / 64), 256, 0, stream>>>(
          W1 + (size_t)e * HID * EDIM, w1t, HID, EDIM);
      gemm_kernel<1><<<(NTOK / 128) * (EDIM / 128), 256, 0, stream>>>(
          xbf, w1t, NTOK, EDIM, HID, b1 + (size_t)e * EDIM, H, nullptr, 0, nullptr);
      cvtT_kernel<<<dim3(HID / 64, EDIM / 64), 256, 0, stream>>>(
          W2 + (size_t)e * EDIM * HID, w2t, EDIM, HID);
      gemm_kernel<2><<<(NTOK / 128) * (HID / 128), 256, 0, stream>>>(
          H, w2t, NTOK, HID, EDIM, nullptr, nullptr, combine, e, out);
    }
  }
}